// Round 5
// baseline (569.947 us; speedup 1.0000x reference)
//
#include <hip/hip_runtime.h>

// Problem constants
#define V_N 1000000
#define J_N 23
#define BLK 256

// Output layout (flat fp32-element offsets):
// verts_batched (4,V,3) | pose (J,3) | joints_out (J,3) | scale (1) | displacement (3) | local_adjust (V,3)
#define OUT_POSE   12000000
#define OUT_JOINTS 12000069
#define OUT_SCALE  12000138
#define OUT_DISP   12000139
#define OUT_LA     12000142   // byte 48000568: 8B-aligned, NOT 16B-aligned

__device__ __constant__ int c_parents[J_N] = {
    -1, 0, 1, 1, 3, 4, 5, 4, 7, 4, 9, 1, 11, 12, 13, 12, 15, 12, 17, 0, 19, 0, 21
};

// ---------------- Stage 1: pose / Rodrigues / FK chain (tiny, 1 block) ----------------
__global__ void stage1_kernel(
    const float* __restrict__ joints_rest,
    const float* __restrict__ j0, const float* __restrict__ j1,
    const float* __restrict__ j2, const float* __restrict__ j3,
    const float* __restrict__ j4, const float* __restrict__ j5,
    const float* __restrict__ j12, const float* __restrict__ j13,
    const float* __restrict__ disp, const float* __restrict__ scale,
    const float* __restrict__ loc,
    float* __restrict__ wsA, float* __restrict__ out)
{
    __shared__ float jr[J_N][3];
    __shared__ float pose[J_N][3];
    __shared__ float R[J_N][9];
    __shared__ float rel[J_N][3];
    __shared__ float G[J_N][12];
    __shared__ float sb[4];
    const int t = threadIdx.x;

    if (t < J_N * 3) {
        ((float*)jr)[t]   = joints_rest[t];
        ((float*)pose)[t] = 0.0f;
    }
    __syncthreads();

    if (t < 27) {   // one thread per (pose row, component)
        const float PI = 3.14159265358979323846f;
        const int   rows[9] = { 0, 1, 2, 3, 11, 4, 5, 12, 13 };
        const float cf[9]   = { PI/2, PI/4, PI/9, PI/3, PI/3, PI/3, PI/3, PI/3, PI/3 };
        int i = t / 3, cmp = t % 3;
        const float* srcs[9];
        srcs[0]=j0; srcs[1]=j1; srcs[2]=j2; srcs[3]=j3; srcs[4]=j3;
        srcs[5]=j4; srcs[6]=j5; srcs[7]=j12; srcs[8]=j13;
        float syz = (rows[i] == 11 && cmp > 0) ? -1.0f : 1.0f;
        pose[rows[i]][cmp] = cf[i] * syz * tanhf(srcs[i][cmp]);
    }
    if (t == 32) {
        sb[0] = 0.0035f * scale[0];
        sb[1] = loc[0] + 0.1f * tanhf(disp[0]);
        sb[2] = loc[1] + 0.1f * tanhf(disp[1]);
        sb[3] = loc[2] + 0.1f * tanhf(disp[2]);
    }
    __syncthreads();

    if (t < J_N) {
        float rx = pose[t][0], ry = pose[t][1], rz = pose[t][2];
        float ang = sqrtf(rx*rx + ry*ry + rz*rz + 1e-12f);
        float inv = 1.0f / ang;
        float x = rx * inv, y = ry * inv, z = rz * inv;
        float s = sinf(ang), c = cosf(ang);
        float K[9]  = { 0.f, -z, y,  z, 0.f, -x,  -y, x, 0.f };
        float K2[9];
        for (int r = 0; r < 3; r++)
            for (int cc = 0; cc < 3; cc++) {
                float a = 0.f;
                for (int k = 0; k < 3; k++) a += K[r*3+k] * K[k*3+cc];
                K2[r*3+cc] = a;
            }
        for (int r = 0; r < 3; r++)
            for (int cc = 0; cc < 3; cc++) {
                float id = (r == cc) ? 1.f : 0.f;
                R[t][r*3+cc] = id + s * K[r*3+cc] + (1.f - c) * K2[r*3+cc];
            }
        int p = c_parents[t];
        for (int cc = 0; cc < 3; cc++)
            rel[t][cc] = (p < 0) ? jr[t][cc] : (jr[t][cc] - jr[p][cc]);
    }
    __syncthreads();

    if (t == 0) {  // serial FK chain (parents precede children)
        for (int r = 0; r < 3; r++) {
            for (int cc = 0; cc < 3; cc++) G[0][r*4+cc] = R[0][r*3+cc];
            G[0][r*4+3] = rel[0][r];
        }
        for (int j = 1; j < J_N; j++) {
            int p = c_parents[j];
            for (int r = 0; r < 3; r++) {
                float g0 = G[p][r*4+0], g1 = G[p][r*4+1], g2 = G[p][r*4+2], g3 = G[p][r*4+3];
                for (int cc = 0; cc < 3; cc++)
                    G[j][r*4+cc] = g0*R[j][0*3+cc] + g1*R[j][1*3+cc] + g2*R[j][2*3+cc];
                G[j][r*4+3] = g0*rel[j][0] + g1*rel[j][1] + g2*rel[j][2] + g3;
            }
        }
    }
    __syncthreads();

    if (t < J_N) {
        for (int r = 0; r < 3; r++) {
            float tc = G[t][r*4+0]*jr[t][0] + G[t][r*4+1]*jr[t][1] + G[t][r*4+2]*jr[t][2];
            wsA[t*12 + r*4 + 0] = G[t][r*4+0];
            wsA[t*12 + r*4 + 1] = G[t][r*4+1];
            wsA[t*12 + r*4 + 2] = G[t][r*4+2];
            wsA[t*12 + r*4 + 3] = G[t][r*4+3] - tc;
            out[OUT_JOINTS + t*3 + r] = sb[0] * G[t][r*4+3] + sb[1+r];
        }
    }
    if (t < J_N * 3) out[OUT_POSE + t] = ((const float*)pose)[t];
    if (t == 0) {
        wsA[276] = sb[0]; wsA[277] = sb[1]; wsA[278] = sb[2]; wsA[279] = sb[3];
        out[OUT_SCALE]  = scale[0];
        out[OUT_DISP+0] = disp[0]; out[OUT_DISP+1] = disp[1]; out[OUT_DISP+2] = disp[2];
    }
}

// ---------------- Stage 2: per-vertex skinning ----------------
// EXACT round-2 body (measured exact HBM traffic: 56.7 MB fetch / 58.7 MB write)
// with ONE change: __launch_bounds__(256,4) -> VGPR<=128 -> 4 blocks/CU.
// Controlled experiment: does concurrency alone trigger the traffic blow-up
// seen in rounds 3/4?
__global__ __launch_bounds__(BLK, 4) void stage2_kernel(
    const float* __restrict__ vt,     // v_template   V*3 f32
    const float* __restrict__ skin,   // skinning     V*J f32
    const float* __restrict__ la,     // local_adjust V*3 f32
    const float* __restrict__ wsA,    // A[23][12] + {s, base.xyz}
    const int* __restrict__ bsp,      // batch_size
    float* __restrict__ out)
{
    __shared__ uint4 s_sk[1472];  // 23552 B
    __shared__ uint4 s_vt[192];   // 3072 B
    __shared__ uint4 s_la[192];
    __shared__ uint4 s_out[192];
    __shared__ float sA[280];

    const int tid = threadIdx.x;
    const int blk = blockIdx.x;
    const int v0  = blk * BLK;

    for (int i = tid; i < 280; i += BLK) sA[i] = wsA[i];
    {
        const uint4* g = (const uint4*)skin + (size_t)blk * 1472;
        int n = min(1472, 5750000 - blk * 1472);     // total skin bytes/16
        for (int i = tid; i < n; i += BLK) s_sk[i] = g[i];
    }
    {
        const uint4* gv = (const uint4*)vt + (size_t)blk * 192;
        const uint4* gl = (const uint4*)la + (size_t)blk * 192;
        int n = min(192, 750000 - blk * 192);        // total vt bytes/16
        for (int i = tid; i < n; i += BLK) { s_vt[i] = gv[i]; s_la[i] = gl[i]; }
    }
    __syncthreads();

    const int v = v0 + tid;
    if (v < V_N) {
        const float* wr = (const float*)s_sk + tid * J_N;  // stride 23: 2-way alias, free
        float acc[12];
        #pragma unroll
        for (int k = 0; k < 12; k++) acc[k] = 0.f;
        #pragma unroll
        for (int j = 0; j < J_N; j++) {
            float w = wr[j];
            const float* Aj = &sA[j * 12];
            #pragma unroll
            for (int k = 0; k < 12; k++) acc[k] = fmaf(w, Aj[k], acc[k]);
        }
        const float* vr = (const float*)s_vt + tid * 3;
        const float* lr = (const float*)s_la + tid * 3;
        float vx = vr[0] + 0.1f * tanhf(lr[0]);
        float vy = vr[1] + 0.1f * tanhf(lr[1]);
        float vz = vr[2] + 0.1f * tanhf(lr[2]);
        float px = acc[0]*vx + acc[1]*vy + acc[2]*vz  + acc[3];
        float py = acc[4]*vx + acc[5]*vy + acc[6]*vz  + acc[7];
        float pz = acc[8]*vx + acc[9]*vy + acc[10]*vz + acc[11];
        float s = sA[276];
        float* so = (float*)s_out + tid * 3;
        so[0] = fmaf(s, px, sA[277]);
        so[1] = fmaf(s, py, sA[278]);
        so[2] = fmaf(s, pz, sA[279]);
    }
    __syncthreads();

    const int nv = min(BLK, V_N - v0);    // 256, or 64 in the last block
    const int nchunk = (nv * 12) >> 4;    // 16B chunks of the verts tile
    const int bsz = bsp[0];
    for (int b = 0; b < bsz; b++) {
        uint4* go = (uint4*)((char*)out + (size_t)b * 12000000u + (size_t)v0 * 12u);
        for (int i = tid; i < nchunk; i += BLK) go[i] = s_out[i];
    }
    {   // local_adjust passthrough; region byte base 48000568 is 8B-aligned only
        unsigned long long* go =
            (unsigned long long*)((char*)out + 48000568ull + (size_t)v0 * 12u);
        const unsigned long long* sl = (const unsigned long long*)s_la;
        const int nu = (nv * 12) >> 3;
        for (int i = tid; i < nu; i += BLK) go[i] = sl[i];
    }
}

extern "C" void kernel_launch(void* const* d_in, const int* in_sizes, int n_in,
                              void* d_out, int out_size, void* d_ws, size_t ws_size,
                              hipStream_t stream) {
    const float* vt   = (const float*)d_in[0];
    const float* skin = (const float*)d_in[1];
    const float* jr   = (const float*)d_in[2];
    const float* j0   = (const float*)d_in[3];
    const float* j1   = (const float*)d_in[4];
    const float* j2   = (const float*)d_in[5];
    const float* j3   = (const float*)d_in[6];
    const float* j4   = (const float*)d_in[7];
    const float* j5   = (const float*)d_in[8];
    const float* j12  = (const float*)d_in[9];
    const float* j13  = (const float*)d_in[10];
    const float* la   = (const float*)d_in[11];
    const float* disp = (const float*)d_in[12];
    const float* sc   = (const float*)d_in[13];
    const float* loc  = (const float*)d_in[14];
    const int* bs     = (const int*)d_in[15];

    float* wsA = (float*)d_ws;
    float* out = (float*)d_out;

    stage1_kernel<<<1, 128, 0, stream>>>(jr, j0, j1, j2, j3, j4, j5, j12, j13,
                                         disp, sc, loc, wsA, out);
    stage2_kernel<<<(V_N + BLK - 1) / BLK, BLK, 0, stream>>>(vt, skin, la, wsA, bs, out);
}

// Round 6
// 219.481 us; speedup vs baseline: 2.5968x; 2.5968x over previous
//
#include <hip/hip_runtime.h>

// Problem constants
#define V_N 1000000
#define J_N 23
#define BLK 256
#define NFULL 3906          // blocks 0..3905 full 256-vertex tiles; block 3906 has 64

// Output layout (flat fp32-element offsets):
// verts_batched (4,V,3) | pose (J,3) | joints_out (J,3) | scale (1) | displacement (3) | local_adjust (V,3)
#define OUT_POSE   12000000
#define OUT_JOINTS 12000069
#define OUT_SCALE  12000138
#define OUT_DISP   12000139
#define OUT_LA     12000142   // byte 48000568: 8B-aligned, NOT 16B-aligned

__device__ __constant__ int c_parents[J_N] = {
    -1, 0, 1, 1, 3, 4, 5, 4, 7, 4, 9, 1, 11, 12, 13, 12, 15, 12, 17, 0, 19, 0, 21
};

// ---------------- Stage 1: pose / Rodrigues / FK chain (tiny, 1 block) ----------------
__global__ void stage1_kernel(
    const float* __restrict__ joints_rest,
    const float* __restrict__ j0, const float* __restrict__ j1,
    const float* __restrict__ j2, const float* __restrict__ j3,
    const float* __restrict__ j4, const float* __restrict__ j5,
    const float* __restrict__ j12, const float* __restrict__ j13,
    const float* __restrict__ disp, const float* __restrict__ scale,
    const float* __restrict__ loc,
    float* __restrict__ wsA, float* __restrict__ out)
{
    __shared__ float jr[J_N][3];
    __shared__ float pose[J_N][3];
    __shared__ float R[J_N][9];
    __shared__ float rel[J_N][3];
    __shared__ float G[J_N][12];
    __shared__ float sb[4];
    const int t = threadIdx.x;

    if (t < J_N * 3) {
        ((float*)jr)[t]   = joints_rest[t];
        ((float*)pose)[t] = 0.0f;
    }
    __syncthreads();

    if (t < 27) {   // one thread per (pose row, component)
        const float PI = 3.14159265358979323846f;
        const int   rows[9] = { 0, 1, 2, 3, 11, 4, 5, 12, 13 };
        const float cf[9]   = { PI/2, PI/4, PI/9, PI/3, PI/3, PI/3, PI/3, PI/3, PI/3 };
        int i = t / 3, cmp = t % 3;
        const float* srcs[9];
        srcs[0]=j0; srcs[1]=j1; srcs[2]=j2; srcs[3]=j3; srcs[4]=j3;
        srcs[5]=j4; srcs[6]=j5; srcs[7]=j12; srcs[8]=j13;
        float syz = (rows[i] == 11 && cmp > 0) ? -1.0f : 1.0f;
        pose[rows[i]][cmp] = cf[i] * syz * tanhf(srcs[i][cmp]);
    }
    if (t == 32) {
        sb[0] = 0.0035f * scale[0];
        sb[1] = loc[0] + 0.1f * tanhf(disp[0]);
        sb[2] = loc[1] + 0.1f * tanhf(disp[1]);
        sb[3] = loc[2] + 0.1f * tanhf(disp[2]);
    }
    __syncthreads();

    if (t < J_N) {
        float rx = pose[t][0], ry = pose[t][1], rz = pose[t][2];
        float ang = sqrtf(rx*rx + ry*ry + rz*rz + 1e-12f);
        float inv = 1.0f / ang;
        float x = rx * inv, y = ry * inv, z = rz * inv;
        float s = sinf(ang), c = cosf(ang);
        float K[9]  = { 0.f, -z, y,  z, 0.f, -x,  -y, x, 0.f };
        float K2[9];
        for (int r = 0; r < 3; r++)
            for (int cc = 0; cc < 3; cc++) {
                float a = 0.f;
                for (int k = 0; k < 3; k++) a += K[r*3+k] * K[k*3+cc];
                K2[r*3+cc] = a;
            }
        for (int r = 0; r < 3; r++)
            for (int cc = 0; cc < 3; cc++) {
                float id = (r == cc) ? 1.f : 0.f;
                R[t][r*3+cc] = id + s * K[r*3+cc] + (1.f - c) * K2[r*3+cc];
            }
        int p = c_parents[t];
        for (int cc = 0; cc < 3; cc++)
            rel[t][cc] = (p < 0) ? jr[t][cc] : (jr[t][cc] - jr[p][cc]);
    }
    __syncthreads();

    if (t == 0) {  // serial FK chain (parents precede children)
        for (int r = 0; r < 3; r++) {
            for (int cc = 0; cc < 3; cc++) G[0][r*4+cc] = R[0][r*3+cc];
            G[0][r*4+3] = rel[0][r];
        }
        for (int j = 1; j < J_N; j++) {
            int p = c_parents[j];
            for (int r = 0; r < 3; r++) {
                float g0 = G[p][r*4+0], g1 = G[p][r*4+1], g2 = G[p][r*4+2], g3 = G[p][r*4+3];
                for (int cc = 0; cc < 3; cc++)
                    G[j][r*4+cc] = g0*R[j][0*3+cc] + g1*R[j][1*3+cc] + g2*R[j][2*3+cc];
                G[j][r*4+3] = g0*rel[j][0] + g1*rel[j][1] + g2*rel[j][2] + g3;
            }
        }
    }
    __syncthreads();

    if (t < J_N) {
        for (int r = 0; r < 3; r++) {
            float tc = G[t][r*4+0]*jr[t][0] + G[t][r*4+1]*jr[t][1] + G[t][r*4+2]*jr[t][2];
            wsA[t*12 + r*4 + 0] = G[t][r*4+0];
            wsA[t*12 + r*4 + 1] = G[t][r*4+1];
            wsA[t*12 + r*4 + 2] = G[t][r*4+2];
            wsA[t*12 + r*4 + 3] = G[t][r*4+3] - tc;
            out[OUT_JOINTS + t*3 + r] = sb[0] * G[t][r*4+3] + sb[1+r];
        }
    }
    if (t < J_N * 3) out[OUT_POSE + t] = ((const float*)pose)[t];
    if (t == 0) {
        wsA[276] = sb[0]; wsA[277] = sb[1]; wsA[278] = sb[2]; wsA[279] = sb[3];
        out[OUT_SCALE]  = scale[0];
        out[OUT_DISP+0] = disp[0]; out[OUT_DISP+1] = disp[1]; out[OUT_DISP+2] = disp[2];
    }
}

// ---------------- Stage 2: per-vertex skinning ----------------
// NO launch_bounds (the min-waves directive triggers scratch spilling on this
// toolchain -> 13x HBM traffic, rounds 3-5). Pressure is kept naturally low:
// A-matrix reads are wave-uniform loads from global (SMEM/scalar path, zero
// VGPR cost). All global traffic LDS-staged in 16B chunks (round-2 pattern,
// measured-exact 56.7/58.7 MB). LDS = 32768 B exactly -> 5 blocks/CU.
__global__ void stage2_kernel(
    const float* __restrict__ vt,     // v_template   V*3 f32
    const float* __restrict__ skin,   // skinning     V*J f32
    const float* __restrict__ la,     // local_adjust V*3 f32
    const float* __restrict__ wsA,    // A[23][12] + {s, base.xyz}  (uniform reads)
    const int* __restrict__ bsp,      // batch_size
    float* __restrict__ out)
{
    __shared__ uint4 s_sk[1472];  // 23552 B
    __shared__ uint4 s_vt[192];   // 3072 B
    __shared__ uint4 s_la[192];   // 3072 B
    __shared__ uint4 s_out[192];  // 3072 B   -> total 32768 B = 5 blocks/CU

    const int tid = threadIdx.x;
    const int blk = blockIdx.x;
    const int v0  = blk * BLK;

    const uint4* g  = (const uint4*)skin + (size_t)blk * 1472;
    const uint4* gv = (const uint4*)vt   + (size_t)blk * 192;
    const uint4* gl = (const uint4*)la   + (size_t)blk * 192;

    if (blk < NFULL) {
        // 8 independent 16B loads in flight before any LDS write
        uint4 r0 = g[tid];
        uint4 r1 = g[tid + 256];
        uint4 r2 = g[tid + 512];
        uint4 r3 = g[tid + 768];
        uint4 r4 = g[tid + 1024];
        uint4 r5, tv, tl;
        if (tid < 192) {
            r5 = g[tid + 1280];
            tv = gv[tid];
            tl = gl[tid];
        }
        s_sk[tid]        = r0;
        s_sk[tid + 256]  = r1;
        s_sk[tid + 512]  = r2;
        s_sk[tid + 768]  = r3;
        s_sk[tid + 1024] = r4;
        if (tid < 192) {
            s_sk[tid + 1280] = r5;
            s_vt[tid] = tv;
            s_la[tid] = tl;
        }
    } else {                          // tail block: 64 verts
        for (int i = tid; i < 368; i += BLK) s_sk[i] = g[i];
        for (int i = tid; i < 48;  i += BLK) { s_vt[i] = gv[i]; s_la[i] = gl[i]; }
    }
    __syncthreads();

    if (v0 + tid < V_N) {
        const float* wr = (const float*)s_sk + tid * J_N;  // stride 23: 2-way alias, free
        float acc[12];
        #pragma unroll
        for (int k = 0; k < 12; k++) acc[k] = 0.f;
        #pragma unroll
        for (int j = 0; j < J_N; j++) {
            float w = wr[j];
            const float* Aj = wsA + j * 12;   // uniform address -> s_load, 0 VGPRs
            #pragma unroll
            for (int k = 0; k < 12; k++) acc[k] = fmaf(w, Aj[k], acc[k]);
        }
        const float* vr = (const float*)s_vt + tid * 3;
        const float* lr = (const float*)s_la + tid * 3;
        float vx = vr[0] + 0.1f * tanhf(lr[0]);
        float vy = vr[1] + 0.1f * tanhf(lr[1]);
        float vz = vr[2] + 0.1f * tanhf(lr[2]);
        float px = acc[0]*vx + acc[1]*vy + acc[2]*vz  + acc[3];
        float py = acc[4]*vx + acc[5]*vy + acc[6]*vz  + acc[7];
        float pz = acc[8]*vx + acc[9]*vy + acc[10]*vz + acc[11];
        float s  = wsA[276];                  // uniform
        float* so = (float*)s_out + tid * 3;
        so[0] = fmaf(s, px, wsA[277]);
        so[1] = fmaf(s, py, wsA[278]);
        so[2] = fmaf(s, pz, wsA[279]);
    }
    __syncthreads();

    const int nv = (blk < NFULL) ? BLK : (V_N - v0);
    const int nchunk = (nv * 12) >> 4;    // 192 or 48
    const int bsz = bsp[0];
    for (int b = 0; b < bsz; b++) {
        uint4* go = (uint4*)((char*)out + (size_t)b * 12000000u + (size_t)v0 * 12u);
        for (int i = tid; i < nchunk; i += BLK) go[i] = s_out[i];
    }
    {   // local_adjust passthrough; region byte base 48000568 is 8B-aligned only
        unsigned long long* go =
            (unsigned long long*)((char*)out + 48000568ull + (size_t)v0 * 12u);
        const unsigned long long* sl = (const unsigned long long*)s_la;
        const int nu = (nv * 12) >> 3;    // 384 or 96
        for (int i = tid; i < nu; i += BLK) go[i] = sl[i];
    }
}

extern "C" void kernel_launch(void* const* d_in, const int* in_sizes, int n_in,
                              void* d_out, int out_size, void* d_ws, size_t ws_size,
                              hipStream_t stream) {
    const float* vt   = (const float*)d_in[0];
    const float* skin = (const float*)d_in[1];
    const float* jr   = (const float*)d_in[2];
    const float* j0   = (const float*)d_in[3];
    const float* j1   = (const float*)d_in[4];
    const float* j2   = (const float*)d_in[5];
    const float* j3   = (const float*)d_in[6];
    const float* j4   = (const float*)d_in[7];
    const float* j5   = (const float*)d_in[8];
    const float* j12  = (const float*)d_in[9];
    const float* j13  = (const float*)d_in[10];
    const float* la   = (const float*)d_in[11];
    const float* disp = (const float*)d_in[12];
    const float* sc   = (const float*)d_in[13];
    const float* loc  = (const float*)d_in[14];
    const int* bs     = (const int*)d_in[15];

    float* wsA = (float*)d_ws;
    float* out = (float*)d_out;

    stage1_kernel<<<1, 128, 0, stream>>>(jr, j0, j1, j2, j3, j4, j5, j12, j13,
                                         disp, sc, loc, wsA, out);
    stage2_kernel<<<(V_N + BLK - 1) / BLK, BLK, 0, stream>>>(vt, skin, la, wsA, bs, out);
}